// Round 1
// baseline (512.841 us; speedup 1.0000x reference)
//
#include <hip/hip_runtime.h>

typedef unsigned short u16;
typedef __attribute__((ext_vector_type(8))) short short8;   // 8 x bf16 (4 VGPRs)
typedef __attribute__((ext_vector_type(4))) float f32x4;    // MFMA accumulator

__device__ __forceinline__ u16 f2bf(float f) {
  union { float f; unsigned u; } c; c.f = f;
  unsigned u = c.u;
  return (u16)((u + 0x7FFFu + ((u >> 16) & 1u)) >> 16);     // round-nearest-even
}

// ---------------------------------------------------------------- prep kernels
__global__ __launch_bounds__(256) void cvt_x_kernel(const float* __restrict__ x,
                                                    u16* __restrict__ xb) {
  int i = blockIdx.x * 256 + threadIdx.x;          // grid sized exactly: 4194304/4
  float4 v = ((const float4*)x)[i];
  uint2 st;
  st.x = (unsigned)f2bf(v.x) | ((unsigned)f2bf(v.y) << 16);
  st.y = (unsigned)f2bf(v.z) | ((unsigned)f2bf(v.w) << 16);
  ((uint2*)xb)[i] = st;
}

// Wt[n][k] = bf16(W[k][n]); K fixed at 512 (idx>>9 = n, idx&511 = k)
__global__ __launch_bounds__(256) void transp_kernel(const float* __restrict__ W,
                                                     u16* __restrict__ Wt,
                                                     int NC, int total) {
  int idx = blockIdx.x * 256 + threadIdx.x;
  if (idx >= total) return;
  int n = idx >> 9, k = idx & 511;
  Wt[idx] = f2bf(W[(size_t)k * NC + n]);
}

// ---------------------------------------------------------------- GEMM (K=512)
// C[M x NC] = A[M x 512] * W[512 x NC], A row-major bf16, W given as Wt[n][k].
// MODE 0: QKV epilogue -> scatter q/k (head-major) and V transposed, +b_qkv
// MODE 1: out-proj epilogue -> fp32 out, +b_o
template<int MODE>
__global__ __launch_bounds__(256) void gemm_kernel(
    const u16* __restrict__ A, const u16* __restrict__ Bt,
    const float* __restrict__ biasv,
    u16* __restrict__ qb, u16* __restrict__ kb, u16* __restrict__ vtb,
    float* __restrict__ outp) {
  __shared__ u16 As[64 * 64];
  __shared__ u16 Bs[64 * 64];
  const int tid = threadIdx.x;
  const int lane = tid & 63;
  const int w = tid >> 6, wm = w >> 1, wn = w & 1;
  const int m0 = blockIdx.y * 64, n0 = blockIdx.x * 64;
  const int r = tid >> 3, s = tid & 7;    // staging: 32 rows x 8 16B-segs / pass
  const int lm = lane & 15, lg = lane >> 4;
  f32x4 acc[2][2] = {};

  for (int k0 = 0; k0 < 512; k0 += 64) {
    __syncthreads();
    *(uint4*)&As[r * 64 + s * 8]        = *(const uint4*)&A[(size_t)(m0 + r) * 512 + k0 + s * 8];
    *(uint4*)&As[(r + 32) * 64 + s * 8] = *(const uint4*)&A[(size_t)(m0 + r + 32) * 512 + k0 + s * 8];
    *(uint4*)&Bs[r * 64 + s * 8]        = *(const uint4*)&Bt[(size_t)(n0 + r) * 512 + k0 + s * 8];
    *(uint4*)&Bs[(r + 32) * 64 + s * 8] = *(const uint4*)&Bt[(size_t)(n0 + r + 32) * 512 + k0 + s * 8];
    __syncthreads();
#pragma unroll
    for (int tc = 0; tc < 2; tc++) {
      short8 bfr[2];
#pragma unroll
      for (int nt = 0; nt < 2; nt++)
        bfr[nt] = *(const short8*)&Bs[(wn * 32 + nt * 16 + lm) * 64 + tc * 32 + lg * 8];
#pragma unroll
      for (int mt = 0; mt < 2; mt++) {
        short8 af = *(const short8*)&As[(wm * 32 + mt * 16 + lm) * 64 + tc * 32 + lg * 8];
#pragma unroll
        for (int nt = 0; nt < 2; nt++)
          acc[mt][nt] = __builtin_amdgcn_mfma_f32_16x16x32_bf16(af, bfr[nt], acc[mt][nt], 0, 0, 0);
      }
    }
  }

#pragma unroll
  for (int mt = 0; mt < 2; mt++) {
#pragma unroll
    for (int nt = 0; nt < 2; nt++) {
      const int col = n0 + wn * 32 + nt * 16 + lm;
      const float bv = biasv[col];
#pragma unroll
      for (int r2 = 0; r2 < 4; r2++) {
        const int row = m0 + wm * 32 + mt * 16 + lg * 4 + r2;  // C/D: col=lane&15, row=(lane>>4)*4+reg
        const float v = acc[mt][nt][r2] + bv;
        if (MODE == 0) {
          const int h = col / 192, rem = col % 192;   // qkv reshape: col = h*192 + which*64 + t
          const int which = rem >> 6, t = rem & 63;
          const int b = row >> 10, n = row & 1023;
          const u16 bb = f2bf(v);
          if (which == 0)      qb[((size_t)(b * 8 + h) * 1024 + n) * 64 + t] = bb;
          else if (which == 1) kb[((size_t)(b * 8 + h) * 1024 + n) * 64 + t] = bb;
          else                 vtb[((size_t)(b * 8 + h) * 64 + t) * 1024 + n] = bb;
        } else {
          outp[(size_t)row * 512 + col] = v;
        }
      }
    }
  }
}

// ---------------------------------------------------------------- attention
// grid (N/32, B), block 512 = 8 waves, wave h handles head h, 32 q-rows/block.
// Flash/online softmax in exp2 domain. Bias staged [h][q][k] in LDS (pad 34).
__global__ __launch_bounds__(512) void attn_kernel(
    const u16* __restrict__ qb, const u16* __restrict__ kb,
    const u16* __restrict__ vtb, const float* __restrict__ bias,
    u16* __restrict__ yb) {
  __shared__ float biasS[8 * 32 * 34];   // 34,816 B
  __shared__ u16 Ps[8 * 32 * 40];        // per-wave P tile, 80B row stride (16B aligned)
  const int tid = threadIdx.x;
  const int lane = tid & 63;
  const int h = tid >> 6;
  const int b = blockIdx.y;
  const int q0 = blockIdx.x * 32;
  const size_t bh = (size_t)b * 8 + h;
  const u16* Q  = qb  + bh * (1024 * 64);
  const u16* K  = kb  + bh * (1024 * 64);
  const u16* VT = vtb + bh * (64 * 1024);
  const int lm = lane & 15, lg = lane >> 4;

  // Q fragments live in registers for the whole kernel (A-layout: m=lane&15, k=lg*8+j)
  short8 aq[2][2];
#pragma unroll
  for (int mt = 0; mt < 2; mt++)
#pragma unroll
    for (int tc = 0; tc < 2; tc++)
      aq[mt][tc] = *(const short8*)&Q[(size_t)(q0 + mt * 16 + lm) * 64 + tc * 32 + lg * 8];

  f32x4 o[2][4] = {};
  float mrow[2][4], lrow[2][4];
#pragma unroll
  for (int mt = 0; mt < 2; mt++)
#pragma unroll
    for (int r2 = 0; r2 < 4; r2++) { mrow[mt][r2] = -1e30f; lrow[mt][r2] = 0.f; }

  const float SC   = 0.125f * 1.4426950408889634f;  // 1/sqrt(64) * log2(e)
  const float LG2E = 1.4426950408889634f;

  // bias staging coords: wave h loads q-rows {h, h+8, h+16, h+24}; lane covers (k, h-half)
  const int kl = lane >> 1, h4 = (lane & 1) * 4;
  float4 pre[4];
#pragma unroll
  for (int rr = 0; rr < 4; rr++) {
    const int qr = h + rr * 8;
    pre[rr] = *(const float4*)&bias[(((size_t)(b * 1024 + q0 + qr)) * 1024 + kl) * 8 + h4];
  }

  for (int kc = 0; kc < 1024; kc += 32) {
    __syncthreads();
#pragma unroll
    for (int rr = 0; rr < 4; rr++) {   // transpose into [h][q][k+pad]
      const int qr = h + rr * 8;
      biasS[(h4 + 0) * 1088 + qr * 34 + kl] = pre[rr].x;
      biasS[(h4 + 1) * 1088 + qr * 34 + kl] = pre[rr].y;
      biasS[(h4 + 2) * 1088 + qr * 34 + kl] = pre[rr].z;
      biasS[(h4 + 3) * 1088 + qr * 34 + kl] = pre[rr].w;
    }
    __syncthreads();
    if (kc + 32 < 1024) {              // prefetch next chunk; latency hidden by compute
#pragma unroll
      for (int rr = 0; rr < 4; rr++) {
        const int qr = h + rr * 8;
        pre[rr] = *(const float4*)&bias[(((size_t)(b * 1024 + q0 + qr)) * 1024 + (kc + 32) + kl) * 8 + h4];
      }
    }

    // S = Q * K^T  (B-layout: n=lane&15 -> key, k=lg*8+j -> t, contiguous 16B)
    f32x4 sf[2][2];
#pragma unroll
    for (int kt = 0; kt < 2; kt++) {
      short8 bk[2];
#pragma unroll
      for (int tc = 0; tc < 2; tc++)
        bk[tc] = *(const short8*)&K[(size_t)(kc + kt * 16 + lm) * 64 + tc * 32 + lg * 8];
#pragma unroll
      for (int mt = 0; mt < 2; mt++) {
        f32x4 c = {0.f, 0.f, 0.f, 0.f};
        c = __builtin_amdgcn_mfma_f32_16x16x32_bf16(aq[mt][0], bk[0], c, 0, 0, 0);
        c = __builtin_amdgcn_mfma_f32_16x16x32_bf16(aq[mt][1], bk[1], c, 0, 0, 0);
        sf[mt][kt] = c;
      }
    }

    // online softmax (base-2 domain) + write P to per-wave LDS
#pragma unroll
    for (int mt = 0; mt < 2; mt++) {
      float pv2[2][4];
      const int qrb = mt * 16 + lg * 4;
#pragma unroll
      for (int kt = 0; kt < 2; kt++)
#pragma unroll
        for (int r2 = 0; r2 < 4; r2++)
          pv2[kt][r2] = sf[mt][kt][r2] * SC +
                        biasS[h * 1088 + (qrb + r2) * 34 + kt * 16 + lm] * LG2E;
      float rmax[4];
#pragma unroll
      for (int r2 = 0; r2 < 4; r2++) rmax[r2] = fmaxf(pv2[0][r2], pv2[1][r2]);
#pragma unroll
      for (int d = 1; d < 16; d <<= 1)
#pragma unroll
        for (int r2 = 0; r2 < 4; r2++)
          rmax[r2] = fmaxf(rmax[r2], __shfl_xor(rmax[r2], d));
      float alpha[4];
#pragma unroll
      for (int r2 = 0; r2 < 4; r2++) {
        const float mn = fmaxf(mrow[mt][r2], rmax[r2]);
        alpha[r2] = exp2f(mrow[mt][r2] - mn);
        mrow[mt][r2] = mn;
      }
      float rsum[4] = {0.f, 0.f, 0.f, 0.f};
#pragma unroll
      for (int kt = 0; kt < 2; kt++)
#pragma unroll
        for (int r2 = 0; r2 < 4; r2++) {
          const float p = exp2f(pv2[kt][r2] - mrow[mt][r2]);
          pv2[kt][r2] = p;
          rsum[r2] += p;
        }
#pragma unroll
      for (int d = 1; d < 16; d <<= 1)
#pragma unroll
        for (int r2 = 0; r2 < 4; r2++)
          rsum[r2] += __shfl_xor(rsum[r2], d);
#pragma unroll
      for (int r2 = 0; r2 < 4; r2++)
        lrow[mt][r2] = lrow[mt][r2] * alpha[r2] + rsum[r2];
#pragma unroll
      for (int nt = 0; nt < 4; nt++)
#pragma unroll
        for (int r2 = 0; r2 < 4; r2++)
          o[mt][nt][r2] *= alpha[r2];
#pragma unroll
      for (int kt = 0; kt < 2; kt++)
#pragma unroll
        for (int r2 = 0; r2 < 4; r2++)
          Ps[h * 1280 + (qrb + r2) * 40 + kt * 16 + lm] = f2bf(pv2[kt][r2]);
    }

    // PV: A = P (from LDS, C->A layout round-trip), B = V^T rows (contiguous 16B)
    // per-wave LDS RAW: DS ops from one wave execute in order; no barrier needed.
    short8 bv[4];
#pragma unroll
    for (int nt = 0; nt < 4; nt++)
      bv[nt] = *(const short8*)&VT[(size_t)(nt * 16 + lm) * 1024 + kc + lg * 8];
#pragma unroll
    for (int mt = 0; mt < 2; mt++) {
      short8 ap = *(const short8*)&Ps[h * 1280 + (mt * 16 + lm) * 40 + lg * 8];
#pragma unroll
      for (int nt = 0; nt < 4; nt++)
        o[mt][nt] = __builtin_amdgcn_mfma_f32_16x16x32_bf16(ap, bv[nt], o[mt][nt], 0, 0, 0);
    }
  }

  // epilogue: y = O / l, bf16, layout [token][h*64 + t]
#pragma unroll
  for (int mt = 0; mt < 2; mt++)
#pragma unroll
    for (int nt = 0; nt < 4; nt++)
#pragma unroll
      for (int r2 = 0; r2 < 4; r2++) {
        const int row = q0 + mt * 16 + lg * 4 + r2;
        const float yv = o[mt][nt][r2] / lrow[mt][r2];
        yb[((size_t)(b * 1024 + row)) * 512 + h * 64 + nt * 16 + lm] = f2bf(yv);
      }
}

// ---------------------------------------------------------------- launch
extern "C" void kernel_launch(void* const* d_in, const int* in_sizes, int n_in,
                              void* d_out, int out_size, void* d_ws, size_t ws_size,
                              hipStream_t stream) {
  const float* x    = (const float*)d_in[0];
  const float* bias = (const float*)d_in[1];
  const float* Wqkv = (const float*)d_in[2];
  const float* bqkv = (const float*)d_in[3];
  const float* Wo   = (const float*)d_in[4];
  const float* bo   = (const float*)d_in[5];
  float* out = (float*)d_out;

  char* p = (char*)d_ws;
  u16* xb    = (u16*)p; p += (size_t)8192 * 512 * 2;        // 8 MB
  u16* wqkvT = (u16*)p; p += (size_t)1536 * 512 * 2;        // 1.5 MB
  u16* woT   = (u16*)p; p += (size_t)512 * 512 * 2;         // 0.5 MB
  u16* qB    = (u16*)p; p += (size_t)8 * 8 * 1024 * 64 * 2; // 8 MB
  u16* kB    = (u16*)p; p += (size_t)8 * 8 * 1024 * 64 * 2; // 8 MB
  u16* vtB   = (u16*)p; p += (size_t)8 * 8 * 64 * 1024 * 2; // 8 MB
  u16* yB    = (u16*)p; p += (size_t)8192 * 512 * 2;        // 8 MB  (total ~44 MB)

  cvt_x_kernel<<<4096, 256, 0, stream>>>(x, xb);
  transp_kernel<<<3072, 256, 0, stream>>>(Wqkv, wqkvT, 1536, 1536 * 512);
  transp_kernel<<<1024, 256, 0, stream>>>(Wo, woT, 512, 512 * 512);
  gemm_kernel<0><<<dim3(24, 128), 256, 0, stream>>>(xb, wqkvT, bqkv, qB, kB, vtB, nullptr);
  attn_kernel<<<dim3(32, 8), 512, 0, stream>>>(qB, kB, vtB, bias, yB);
  gemm_kernel<1><<<dim3(8, 128), 256, 0, stream>>>(yB, woT, bo, nullptr, nullptr, nullptr, out);
}